// Round 1
// baseline (485.283 us; speedup 1.0000x reference)
//
#include <hip/hip_runtime.h>
#include <hip/hip_bf16.h>

#define N 8192
#define FD 128

typedef __attribute__((ext_vector_type(4))) float f4;
typedef __attribute__((ext_vector_type(4))) int i32x4;
typedef __attribute__((ext_vector_type(4))) unsigned int u32x4;
typedef __attribute__((ext_vector_type(4))) unsigned short us4;
typedef __attribute__((ext_vector_type(8))) __bf16 bf16x8;

__device__ __forceinline__ unsigned short bfbits(float x){
  __bf16 b = (__bf16)x;
  return __builtin_bit_cast(unsigned short, b);
}

// ---------------- K1: Wh = h @ W  (f32), plus WhbT[f][i] (bf16) ----------------
__global__ __launch_bounds__(256) void k1_wh(const float* __restrict__ h,
                                             const float* __restrict__ W,
                                             float* __restrict__ Wh,
                                             unsigned short* __restrict__ WhbT){
  __shared__ float Wl[64*128];   // half of W (k-split), 32KB
  __shared__ float hT[128*33];   // h tile transposed [k][r], padded stride 33
  int t = threadIdx.x;
  int i0 = blockIdx.x * 32;
  {
    int r  = t >> 3;           // 0..31
    int k0 = (t & 7) * 16;     // 0,16,...,112
    const f4* src = (const f4*)&h[(size_t)(i0 + r)*FD + k0];
    #pragma unroll
    for (int q = 0; q < 4; ++q){
      f4 v = src[q];
      #pragma unroll
      for (int e = 0; e < 4; ++e) hT[(k0 + q*4 + e)*33 + r] = v[e];
    }
  }
  int f0 = (t & 31) * 4;   // 0..124
  int r0 = (t >> 5) * 4;   // 0..28
  float acc[4][4] = {};
  for (int half = 0; half < 2; ++half){
    __syncthreads();
    #pragma unroll
    for (int v = 0; v < 8; ++v){
      int idx = (v*256 + t)*4;
      *(f4*)&Wl[idx] = *(const f4*)&W[half*8192 + idx];
    }
    __syncthreads();
    for (int k2 = 0; k2 < 64; ++k2){
      f4 wv = *(const f4*)&Wl[k2*FD + f0];
      f4 hv = *(const f4*)&hT[(half*64 + k2)*33 + r0];
      #pragma unroll
      for (int ri = 0; ri < 4; ++ri)
        #pragma unroll
        for (int fi = 0; fi < 4; ++fi)
          acc[ri][fi] = __builtin_fmaf(hv[ri], wv[fi], acc[ri][fi]);
    }
  }
  #pragma unroll
  for (int ri = 0; ri < 4; ++ri){
    f4 o = {acc[ri][0], acc[ri][1], acc[ri][2], acc[ri][3]};
    *(f4*)&Wh[(size_t)(i0 + r0 + ri)*FD + f0] = o;
  }
  #pragma unroll
  for (int fi = 0; fi < 4; ++fi){
    us4 o;
    #pragma unroll
    for (int ri = 0; ri < 4; ++ri) o[ri] = bfbits(acc[ri][fi]);
    *(us4*)&WhbT[(size_t)(f0 + fi)*N + i0 + r0] = o;
  }
}

// ---------------- K2: s1 = Wh@a1, s2 = Wh@a2 ----------------
__global__ __launch_bounds__(256) void k2_s(const float* __restrict__ Wh,
                                            const float* __restrict__ a,
                                            float* __restrict__ s1,
                                            float* __restrict__ s2){
  int i = blockIdx.x*256 + threadIdx.x;
  const f4* row = (const f4*)&Wh[(size_t)i*FD];
  const f4* a1 = (const f4*)a;
  const f4* a2 = (const f4*)&a[FD];
  float x1 = 0.f, x2 = 0.f;
  #pragma unroll
  for (int q = 0; q < 32; ++q){
    f4 w = row[q], va = a1[q], vb = a2[q];
    #pragma unroll
    for (int e = 0; e < 4; ++e){
      x1 = __builtin_fmaf(w[e], va[e], x1);
      x2 = __builtin_fmaf(w[e], vb[e], x2);
    }
  }
  s1[i] = x1; s2[i] = x2;
}

// ---------------- K3: M2 = max(s2) ----------------
__global__ __launch_bounds__(256) void k3_max(const float* __restrict__ s2,
                                              float* __restrict__ M2){
  __shared__ float red[4];
  int t = threadIdx.x;
  float m = -3.0e38f;
  for (int i = t; i < N; i += 256) m = fmaxf(m, s2[i]);
  #pragma unroll
  for (int d = 1; d < 64; d <<= 1) m = fmaxf(m, __shfl_xor(m, d, 64));
  if ((t & 63) == 0) red[t >> 6] = m;
  __syncthreads();
  if (t == 0) *M2 = fmaxf(fmaxf(red[0], red[1]), fmaxf(red[2], red[3]));
}

// ---------------- K4: fused masked-softmax numerator/denominator ----------------
// Per wave: 32 rows (two 16-row MFMA tiles), full 128 features, one j-chunk.
// A-frag (16x16x32 bf16): row = lane&15, k = (lane>>4)*8 + e
// B-frag:                 col = lane&15, k = (lane>>4)*8 + e
// C:                      col = lane&15, row = (lane>>4)*4 + reg
__global__ __launch_bounds__(256,2) void k4_flash(const int* __restrict__ adj,
    const unsigned short* __restrict__ WhbT,
    const float* __restrict__ s1, const float* __restrict__ s2,
    const float* __restrict__ M2p,
    float* __restrict__ partial, float* __restrict__ denomp, int njc){
  int t = threadIdx.x;
  int wv = t >> 6, lane = t & 63;
  int lrow = lane & 15, lgrp = lane >> 4;
  int i0 = blockIdx.x * 128 + wv * 32;
  int jlen = N / njc;
  int jstart = blockIdx.y * jlen;
  float M2 = *M2p;
  float s1a = s1[i0 + lrow], s1b = s1[i0 + 16 + lrow];
  float ea = s1a + M2, eb = s1b + M2;
  float ma = fmaxf(ea, 0.2f*ea), mb = fmaxf(eb, 0.2f*eb);  // valid row-max bound

  f4 acc[2][8];
  #pragma unroll
  for (int x = 0; x < 2; ++x)
    #pragma unroll
    for (int n = 0; n < 8; ++n) acc[x][n] = (f4){0.f,0.f,0.f,0.f};
  float da = 0.f, db = 0.f;

  const i32x4* adj4 = (const i32x4*)adj;
  size_t rowa = ((size_t)(i0 + lrow) * N) >> 2;   // in i32x4 units
  size_t rowb = rowa + (size_t)(16*N)/4;

  for (int js = 0; js < jlen/32; ++js){
    int jb = jstart + js*32 + lgrp*8;   // this lane's 8 consecutive j's
    i32x4 A0 = adj4[rowa + (jb>>2)];
    i32x4 A1 = adj4[rowa + (jb>>2) + 1];
    i32x4 B0 = adj4[rowb + (jb>>2)];
    i32x4 B1 = adj4[rowb + (jb>>2) + 1];
    f4 s2a = *(const f4*)&s2[jb];
    f4 s2b = *(const f4*)&s2[jb+4];
    u32x4 braw[8];
    #pragma unroll
    for (int n = 0; n < 8; ++n)
      braw[n] = *(const u32x4*)&WhbT[(size_t)(n*16 + lrow)*N + jb];

    bf16x8 fa, fb;
    #pragma unroll
    for (int e = 0; e < 8; ++e){
      float sj = (e < 4) ? s2a[e & 3] : s2b[e & 3];
      int av = (e < 4) ? A0[e & 3] : A1[e & 3];
      int bv = (e < 4) ? B0[e & 3] : B1[e & 3];
      float t0 = s1a + sj;
      float p0 = av ? __expf(fmaxf(t0, 0.2f*t0) - ma) : 0.f;
      float t1 = s1b + sj;
      float p1 = bv ? __expf(fmaxf(t1, 0.2f*t1) - mb) : 0.f;
      da += p0; db += p1;
      fa[e] = (__bf16)p0; fb[e] = (__bf16)p1;
    }
    #pragma unroll
    for (int n = 0; n < 8; ++n){
      bf16x8 bb = __builtin_bit_cast(bf16x8, braw[n]);
      acc[0][n] = __builtin_amdgcn_mfma_f32_16x16x32_bf16(fa, bb, acc[0][n], 0, 0, 0);
      acc[1][n] = __builtin_amdgcn_mfma_f32_16x16x32_bf16(fb, bb, acc[1][n], 0, 0, 0);
    }
  }

  da += __shfl_xor(da, 16, 64); da += __shfl_xor(da, 32, 64);
  db += __shfl_xor(db, 16, 64); db += __shfl_xor(db, 32, 64);
  if (lgrp == 0){
    denomp[(size_t)blockIdx.y*N + i0 + lrow] = da;
    denomp[(size_t)blockIdx.y*N + i0 + 16 + lrow] = db;
  }
  float* pb = partial + (size_t)blockIdx.y * N * FD;
  #pragma unroll
  for (int x = 0; x < 2; ++x)
    #pragma unroll
    for (int n = 0; n < 8; ++n)
      #pragma unroll
      for (int r = 0; r < 4; ++r)
        pb[(size_t)(i0 + x*16 + lgrp*4 + r)*FD + n*16 + lrow] = acc[x][n][r];
}

// ---------------- K5: combine partials, divide ----------------
__global__ __launch_bounds__(256) void k5_fin(const float* __restrict__ partial,
    const float* __restrict__ denomp, float* __restrict__ out, int njc){
  int g = blockIdx.x*256 + threadIdx.x;
  int i = g >> 7;
  float num = 0.f, den = 0.f;
  for (int c = 0; c < njc; ++c) num += partial[(size_t)c*N*FD + g];
  for (int c = 0; c < njc; ++c) den += denomp[(size_t)c*N + i];
  out[g] = num / den;
}

extern "C" void kernel_launch(void* const* d_in, const int* in_sizes, int n_in,
                              void* d_out, int out_size, void* d_ws, size_t ws_size,
                              hipStream_t stream){
  const float* h   = (const float*)d_in[0];
  const int*   adj = (const int*)d_in[1];
  const float* W   = (const float*)d_in[2];
  const float* a   = (const float*)d_in[3];
  float* out = (float*)d_out;
  char* ws = (char*)d_ws;

  unsigned short* WhbT = (unsigned short*)ws;            // 2 MB: WhbT[128][8192] bf16
  float* Wh = (float*)(ws + (size_t)(2u<<20));           // 4 MB
  float* s1 = (float*)(ws + (size_t)(6u<<20));           // 32 KB
  float* s2 = (float*)(ws + (size_t)(6u<<20) + 32768);   // 32 KB
  float* M2 = (float*)(ws + (size_t)(6u<<20) + 65536);   // 4 B
  float* denomp  = (float*)(ws + (size_t)(7u<<20));      // njc*32 KB
  float* partial = (float*)(ws + (size_t)(8u<<20));      // njc*4 MB

  size_t chunk = (size_t)N * FD * sizeof(float);         // 4 MB
  int njc = 1;
  if (ws_size > ((size_t)(8u<<20))){
    size_t m = (ws_size - (size_t)(8u<<20)) / chunk;
    njc = (m >= 16) ? 16 : (m >= 8) ? 8 : (m >= 4) ? 4 : (m >= 2) ? 2 : 1;
  }

  hipLaunchKernelGGL(k1_wh,  dim3(256),      dim3(256), 0, stream, h, W, Wh, WhbT);
  hipLaunchKernelGGL(k2_s,   dim3(32),       dim3(256), 0, stream, Wh, a, s1, s2);
  hipLaunchKernelGGL(k3_max, dim3(1),        dim3(256), 0, stream, s2, M2);
  hipLaunchKernelGGL(k4_flash, dim3(64, njc), dim3(256), 0, stream,
                     adj, WhbT, s1, s2, M2, partial, denomp, njc);
  hipLaunchKernelGGL(k5_fin, dim3(N*FD/256), dim3(256), 0, stream, partial, denomp, out, njc);
}